// Round 1
// baseline (784.118 us; speedup 1.0000x reference)
//
#include <hip/hip_runtime.h>
#include <math.h>

#define NN 50000
#define EE 800000
#define HH 64
#define GG 512

// ---------------- degree / norm ----------------

__global__ void k_deg(const int* __restrict__ dst, int* __restrict__ deg) {
    int e = blockIdx.x * blockDim.x + threadIdx.x;
    if (e < EE) atomicAdd(&deg[dst[e]], 1);
}

__global__ void k_dinv(const int* __restrict__ deg, float* __restrict__ dinv) {
    int i = blockIdx.x * blockDim.x + threadIdx.x;
    if (i < NN) dinv[i] = 1.0f / sqrtf((float)(deg[i] + 1));  // +1 self-loop
}

// ---------------- dense transform: t = act(x) @ W ----------------
// block = 256 threads, 32 rows per block. W (64x64) + 32x65-padded X tile in LDS.

template<bool RELU>
__global__ void __launch_bounds__(256) k_xform(const float* __restrict__ x,
                                               const float* __restrict__ W,
                                               float* __restrict__ t) {
    __shared__ float sW[64 * 64];   // 16 KB
    __shared__ float sX[32 * 65];   // padded stride 65 -> conflict-free reads
    int tid = threadIdx.x;
    for (int k = tid; k < 64 * 64; k += 256) sW[k] = W[k];
    int row0 = blockIdx.x * 32;
    for (int v = tid; v < 32 * 16; v += 256) {
        int r  = v >> 4;
        int k4 = (v & 15) * 4;
        int row = row0 + r;
        float4 val = make_float4(0.f, 0.f, 0.f, 0.f);
        if (row < NN) val = *(const float4*)(x + (size_t)row * 64 + k4);
        if (RELU) {
            val.x = fmaxf(val.x, 0.f); val.y = fmaxf(val.y, 0.f);
            val.z = fmaxf(val.z, 0.f); val.w = fmaxf(val.w, 0.f);
        }
        sX[r * 65 + k4 + 0] = val.x;
        sX[r * 65 + k4 + 1] = val.y;
        sX[r * 65 + k4 + 2] = val.z;
        sX[r * 65 + k4 + 3] = val.w;
    }
    __syncthreads();
    int r  = tid >> 3;        // 0..31
    int c0 = (tid & 7) * 8;   // 0,8,...,56
    float acc[8] = {0.f, 0.f, 0.f, 0.f, 0.f, 0.f, 0.f, 0.f};
    for (int k = 0; k < 64; ++k) {
        float xv = sX[r * 65 + k];
#pragma unroll
        for (int j = 0; j < 8; ++j) acc[j] = fmaf(xv, sW[k * 64 + c0 + j], acc[j]);
    }
    int row = row0 + r;
    if (row < NN) {
        float4* o = (float4*)(t + (size_t)row * 64 + c0);
        o[0] = make_float4(acc[0], acc[1], acc[2], acc[3]);
        o[1] = make_float4(acc[4], acc[5], acc[6], acc[7]);
    }
}

// ---------------- agg init: self-loop + bias ----------------

__global__ void k_init(const float* __restrict__ t, const float* __restrict__ dinv,
                       const float* __restrict__ b, float* __restrict__ agg) {
    int idx = blockIdx.x * blockDim.x + threadIdx.x;
    if (idx >= NN * 64) return;
    int i = idx >> 6, c = idx & 63;
    float dv = dinv[i];
    agg[idx] = fmaf(t[idx], dv * dv, b[c]);
}

// ---------------- edge scatter: one wave per edge ----------------

__global__ void __launch_bounds__(256) k_scatter(const float* __restrict__ t,
                                                 const float* __restrict__ dinv,
                                                 const int* __restrict__ src,
                                                 const int* __restrict__ dst,
                                                 float* __restrict__ agg) {
    long long idx = (long long)blockIdx.x * blockDim.x + threadIdx.x;
    int e = (int)(idx >> 6);
    int c = (int)(idx & 63);
    if (e >= EE) return;
    int s = src[e], d = dst[e];
    float coef = dinv[s] * dinv[d];
    atomicAdd(&agg[(size_t)d * 64 + c], t[(size_t)s * 64 + c] * coef);
}

// ---------------- pooling ----------------

__global__ void k_pool(const float* __restrict__ h, const int* __restrict__ batch,
                       float* __restrict__ pooled) {
    int idx = blockIdx.x * blockDim.x + threadIdx.x;
    if (idx >= NN * 64) return;
    int i = idx >> 6, c = idx & 63;
    float v = fmaxf(h[idx], 0.0f);   // relu of conv3 folded here
    atomicAdd(&pooled[(size_t)batch[i] * 64 + c], v);
}

__global__ void k_cnt(const int* __restrict__ batch, int* __restrict__ cnt) {
    int i = blockIdx.x * blockDim.x + threadIdx.x;
    if (i < NN) atomicAdd(&cnt[batch[i]], 1);
}

// ---------------- head: per-graph MLP ----------------
// block = 64 threads (1 wave), one graph per block

__global__ void __launch_bounds__(64) k_head(const float* __restrict__ pooled,
                                             const int* __restrict__ cnt,
                                             const float* __restrict__ w1,
                                             const float* __restrict__ b1,
                                             const float* __restrict__ w2,
                                             const float* __restrict__ b2,
                                             float* __restrict__ out) {
    int g = blockIdx.x;
    int c = threadIdx.x;
    __shared__ float sp[64];
    float cf = fmaxf((float)cnt[g], 1.0f);
    sp[c] = pooled[(size_t)g * 64 + c] / cf;
    __syncthreads();
    float acc = b1[c];
    for (int k = 0; k < 64; ++k) acc = fmaf(sp[k], w1[k * 64 + c], acc);
    float h1 = fmaxf(acc, 0.0f);
    float p = h1 * w2[c];
#pragma unroll
    for (int off = 32; off > 0; off >>= 1) p += __shfl_down(p, off);
    if (c == 0) out[g] = p + b2[0];
}

// ---------------- launch ----------------

extern "C" void kernel_launch(void* const* d_in, const int* in_sizes, int n_in,
                              void* d_out, int out_size, void* d_ws, size_t ws_size,
                              hipStream_t stream) {
    const float* x      = (const float*)d_in[0];
    const int*   ei     = (const int*)d_in[1];
    const int*   batch  = (const int*)d_in[2];
    const float* W0     = (const float*)d_in[3];
    const float* b0     = (const float*)d_in[4];
    const float* W1     = (const float*)d_in[5];
    const float* b1     = (const float*)d_in[6];
    const float* W2     = (const float*)d_in[7];
    const float* b2     = (const float*)d_in[8];
    const float* lin1w  = (const float*)d_in[9];
    const float* lin1b  = (const float*)d_in[10];
    const float* lin2w  = (const float*)d_in[11];
    const float* lin2b  = (const float*)d_in[12];
    float* out = (float*)d_out;

    const int* src = ei;
    const int* dst = ei + EE;

    char* ws = (char*)d_ws;
    size_t off = 0;
    auto carve = [&](size_t bytes) {
        void* p = ws + off;
        off = (off + bytes + 255) & ~(size_t)255;
        return p;
    };
    int*   deg    = (int*)carve((size_t)NN * 4);
    float* dinv   = (float*)carve((size_t)NN * 4);
    float* bufT   = (float*)carve((size_t)NN * 64 * 4);
    float* bufA   = (float*)carve((size_t)NN * 64 * 4);
    float* bufB   = (float*)carve((size_t)NN * 64 * 4);
    float* pooled = (float*)carve((size_t)GG * 64 * 4);
    int*   cnt    = (int*)carve((size_t)GG * 4);

    hipMemsetAsync(deg, 0, (size_t)NN * 4, stream);
    hipMemsetAsync(pooled, 0, (size_t)GG * 64 * 4, stream);
    hipMemsetAsync(cnt, 0, (size_t)GG * 4, stream);

    k_deg<<<(EE + 255) / 256, 256, 0, stream>>>(dst, deg);
    k_dinv<<<(NN + 255) / 256, 256, 0, stream>>>(deg, dinv);

    const int xgrid = (NN + 31) / 32;
    const int egrid = (int)(((long long)EE * 64) / 256);
    const int ngrid = (NN * 64 + 255) / 256;

    // layer 0: x -> bufA
    k_xform<false><<<xgrid, 256, 0, stream>>>(x, W0, bufT);
    k_init<<<ngrid, 256, 0, stream>>>(bufT, dinv, b0, bufA);
    k_scatter<<<egrid, 256, 0, stream>>>(bufT, dinv, src, dst, bufA);

    // layer 1: relu(bufA) -> bufB
    k_xform<true><<<xgrid, 256, 0, stream>>>(bufA, W1, bufT);
    k_init<<<ngrid, 256, 0, stream>>>(bufT, dinv, b1, bufB);
    k_scatter<<<egrid, 256, 0, stream>>>(bufT, dinv, src, dst, bufB);

    // layer 2: relu(bufB) -> bufA
    k_xform<true><<<xgrid, 256, 0, stream>>>(bufB, W2, bufT);
    k_init<<<ngrid, 256, 0, stream>>>(bufT, dinv, b2, bufA);
    k_scatter<<<egrid, 256, 0, stream>>>(bufT, dinv, src, dst, bufA);

    // pooling (relu folded) + head
    k_pool<<<ngrid, 256, 0, stream>>>(bufA, batch, pooled);
    k_cnt<<<(NN + 255) / 256, 256, 0, stream>>>(batch, cnt);
    k_head<<<GG, 64, 0, stream>>>(pooled, cnt, lin1w, lin1b, lin2w, lin2b, out);
}

// Round 2
// 511.554 us; speedup vs baseline: 1.5328x; 1.5328x over previous
//
#include <hip/hip_runtime.h>
#include <math.h>

#define NN 50000
#define EE 800000
#define HH 64
#define GG 512

// ---------------- degree / norm ----------------

__global__ void k_deg(const int* __restrict__ dst, int* __restrict__ deg) {
    int e = blockIdx.x * blockDim.x + threadIdx.x;
    if (e < EE) atomicAdd(&deg[dst[e]], 1);
}

__global__ void k_dinv(const int* __restrict__ deg, float* __restrict__ dinv) {
    int i = blockIdx.x * blockDim.x + threadIdx.x;
    if (i < NN) dinv[i] = 1.0f / sqrtf((float)(deg[i] + 1));  // +1 self-loop
}

// ---------------- exclusive prefix sum over deg -> rowptr (single block) ----------------

__global__ void __launch_bounds__(1024) k_scan(const int* __restrict__ deg,
                                               int* __restrict__ rowptr) {
    __shared__ int s[1024];
    __shared__ int carry;
    int tid = threadIdx.x;
    if (tid == 0) carry = 0;
    __syncthreads();
    for (int base = 0; base < NN; base += 1024) {
        int i = base + tid;
        int v = (i < NN) ? deg[i] : 0;
        s[tid] = v;
        __syncthreads();
#pragma unroll
        for (int off = 1; off < 1024; off <<= 1) {
            int tv = (tid >= off) ? s[tid - off] : 0;
            __syncthreads();
            s[tid] += tv;
            __syncthreads();
        }
        int incl = s[tid];
        if (i < NN) rowptr[i] = carry + incl - v;   // exclusive
        __syncthreads();
        if (tid == 1023) carry += s[1023];
        __syncthreads();
    }
    if (tid == 0) rowptr[NN] = carry;
}

// ---------------- CSR fill: per-edge slot by atomic cursor ----------------

__global__ void k_fill(const int* __restrict__ src, const int* __restrict__ dst,
                       const float* __restrict__ dinv, const int* __restrict__ rowptr,
                       int* __restrict__ cursor, int* __restrict__ csr_src,
                       float* __restrict__ csr_coef) {
    int e = blockIdx.x * blockDim.x + threadIdx.x;
    if (e >= EE) return;
    int s = src[e], d = dst[e];
    int pos = atomicAdd(&cursor[d], 1);
    int o = rowptr[d] + pos;
    csr_src[o] = s;
    csr_coef[o] = dinv[s] * dinv[d];
}

// ---------------- dense transform: t = act(x) @ W ----------------

template<bool RELU>
__global__ void __launch_bounds__(256) k_xform(const float* __restrict__ x,
                                               const float* __restrict__ W,
                                               float* __restrict__ t) {
    __shared__ float sW[64 * 64];   // 16 KB
    __shared__ float sX[32 * 65];   // padded
    int tid = threadIdx.x;
    for (int k = tid; k < 64 * 64; k += 256) sW[k] = W[k];
    int row0 = blockIdx.x * 32;
    for (int v = tid; v < 32 * 16; v += 256) {
        int r  = v >> 4;
        int k4 = (v & 15) * 4;
        int row = row0 + r;
        float4 val = make_float4(0.f, 0.f, 0.f, 0.f);
        if (row < NN) val = *(const float4*)(x + (size_t)row * 64 + k4);
        if (RELU) {
            val.x = fmaxf(val.x, 0.f); val.y = fmaxf(val.y, 0.f);
            val.z = fmaxf(val.z, 0.f); val.w = fmaxf(val.w, 0.f);
        }
        sX[r * 65 + k4 + 0] = val.x;
        sX[r * 65 + k4 + 1] = val.y;
        sX[r * 65 + k4 + 2] = val.z;
        sX[r * 65 + k4 + 3] = val.w;
    }
    __syncthreads();
    int r  = tid >> 3;        // 0..31
    int c0 = (tid & 7) * 8;   // 0,8,...,56
    float acc[8] = {0.f, 0.f, 0.f, 0.f, 0.f, 0.f, 0.f, 0.f};
    for (int k = 0; k < 64; ++k) {
        float xv = sX[r * 65 + k];
#pragma unroll
        for (int j = 0; j < 8; ++j) acc[j] = fmaf(xv, sW[k * 64 + c0 + j], acc[j]);
    }
    int row = row0 + r;
    if (row < NN) {
        float4* o = (float4*)(t + (size_t)row * 64 + c0);
        o[0] = make_float4(acc[0], acc[1], acc[2], acc[3]);
        o[1] = make_float4(acc[4], acc[5], acc[6], acc[7]);
    }
}

// ---------------- CSR gather: one wave per node, fused self-loop + bias ----------------

template<bool POOL>
__global__ void __launch_bounds__(256) k_gather(const float* __restrict__ t,
                                                const float* __restrict__ dinv,
                                                const int* __restrict__ rowptr,
                                                const int* __restrict__ csr_src,
                                                const float* __restrict__ csr_coef,
                                                const float* __restrict__ b,
                                                const int* __restrict__ batch,
                                                float* __restrict__ out) {
    int wave = (blockIdx.x * blockDim.x + threadIdx.x) >> 6;
    int c = threadIdx.x & 63;
    if (wave >= NN) return;
    int i = wave;
    float dv = dinv[i];
    float acc = fmaf(t[(size_t)i * 64 + c], dv * dv, b[c]);
    float acc2 = 0.0f;
    int e = rowptr[i], end = rowptr[i + 1];
    for (; e + 1 < end; e += 2) {
        int   s0 = csr_src[e],     s1 = csr_src[e + 1];
        float f0 = csr_coef[e],    f1 = csr_coef[e + 1];
        acc  = fmaf(t[(size_t)s0 * 64 + c], f0, acc);
        acc2 = fmaf(t[(size_t)s1 * 64 + c], f1, acc2);
    }
    if (e < end) acc = fmaf(t[(size_t)csr_src[e] * 64 + c], csr_coef[e], acc);
    acc += acc2;
    if (POOL) {
        // relu + mean-pool accumulate (h3 never materialized)
        atomicAdd(&out[(size_t)batch[i] * 64 + c], fmaxf(acc, 0.0f));
    } else {
        out[(size_t)i * 64 + c] = acc;
    }
}

__global__ void k_cnt(const int* __restrict__ batch, int* __restrict__ cnt) {
    int i = blockIdx.x * blockDim.x + threadIdx.x;
    if (i < NN) atomicAdd(&cnt[batch[i]], 1);
}

// ---------------- head: per-graph MLP, one wave per graph ----------------

__global__ void __launch_bounds__(64) k_head(const float* __restrict__ pooled,
                                             const int* __restrict__ cnt,
                                             const float* __restrict__ w1,
                                             const float* __restrict__ b1,
                                             const float* __restrict__ w2,
                                             const float* __restrict__ b2,
                                             float* __restrict__ out) {
    int g = blockIdx.x;
    int c = threadIdx.x;
    __shared__ float sp[64];
    float cf = fmaxf((float)cnt[g], 1.0f);
    sp[c] = pooled[(size_t)g * 64 + c] / cf;
    __syncthreads();
    float acc = b1[c];
    for (int k = 0; k < 64; ++k) acc = fmaf(sp[k], w1[k * 64 + c], acc);
    float h1 = fmaxf(acc, 0.0f);
    float p = h1 * w2[c];
#pragma unroll
    for (int off = 32; off > 0; off >>= 1) p += __shfl_down(p, off);
    if (c == 0) out[g] = p + b2[0];
}

// ---------------- launch ----------------

extern "C" void kernel_launch(void* const* d_in, const int* in_sizes, int n_in,
                              void* d_out, int out_size, void* d_ws, size_t ws_size,
                              hipStream_t stream) {
    const float* x      = (const float*)d_in[0];
    const int*   ei     = (const int*)d_in[1];
    const int*   batch  = (const int*)d_in[2];
    const float* W0     = (const float*)d_in[3];
    const float* b0     = (const float*)d_in[4];
    const float* W1     = (const float*)d_in[5];
    const float* b1     = (const float*)d_in[6];
    const float* W2     = (const float*)d_in[7];
    const float* b2     = (const float*)d_in[8];
    const float* lin1w  = (const float*)d_in[9];
    const float* lin1b  = (const float*)d_in[10];
    const float* lin2w  = (const float*)d_in[11];
    const float* lin2b  = (const float*)d_in[12];
    float* out = (float*)d_out;

    const int* src = ei;
    const int* dst = ei + EE;

    char* ws = (char*)d_ws;
    size_t off = 0;
    auto carve = [&](size_t bytes) {
        void* p = ws + off;
        off = (off + bytes + 255) & ~(size_t)255;
        return p;
    };
    int*   deg      = (int*)carve((size_t)NN * 4);
    float* dinv     = (float*)carve((size_t)NN * 4);
    int*   rowptr   = (int*)carve((size_t)(NN + 1) * 4);
    int*   cursor   = (int*)carve((size_t)NN * 4);
    int*   csr_src  = (int*)carve((size_t)EE * 4);
    float* csr_coef = (float*)carve((size_t)EE * 4);
    float* bufT     = (float*)carve((size_t)NN * 64 * 4);
    float* bufA     = (float*)carve((size_t)NN * 64 * 4);
    float* pooled   = (float*)carve((size_t)GG * 64 * 4);
    int*   cnt      = (int*)carve((size_t)GG * 4);

    hipMemsetAsync(deg, 0, (size_t)NN * 4, stream);
    hipMemsetAsync(cursor, 0, (size_t)NN * 4, stream);
    hipMemsetAsync(pooled, 0, (size_t)GG * 64 * 4, stream);
    hipMemsetAsync(cnt, 0, (size_t)GG * 4, stream);

    // ---- CSR build (per launch; no state may persist) ----
    k_deg <<<(EE + 255) / 256, 256, 0, stream>>>(dst, deg);
    k_dinv<<<(NN + 255) / 256, 256, 0, stream>>>(deg, dinv);
    k_scan<<<1, 1024, 0, stream>>>(deg, rowptr);
    k_fill<<<(EE + 255) / 256, 256, 0, stream>>>(src, dst, dinv, rowptr, cursor,
                                                 csr_src, csr_coef);
    k_cnt <<<(NN + 255) / 256, 256, 0, stream>>>(batch, cnt);

    const int xgrid = (NN + 31) / 32;
    const int ggrid = (NN * 64 + 255) / 256;   // one 64-lane wave per node

    // layer 0: x -> bufA
    k_xform<false><<<xgrid, 256, 0, stream>>>(x, W0, bufT);
    k_gather<false><<<ggrid, 256, 0, stream>>>(bufT, dinv, rowptr, csr_src, csr_coef,
                                               b0, batch, bufA);
    // layer 1: relu(bufA) -> bufA (in-place safe: gather reads only bufT)
    k_xform<true><<<xgrid, 256, 0, stream>>>(bufA, W1, bufT);
    k_gather<false><<<ggrid, 256, 0, stream>>>(bufT, dinv, rowptr, csr_src, csr_coef,
                                               b1, batch, bufA);
    // layer 2: relu(bufA) -> pooled directly (relu + mean-pool fused)
    k_xform<true><<<xgrid, 256, 0, stream>>>(bufA, W2, bufT);
    k_gather<true><<<ggrid, 256, 0, stream>>>(bufT, dinv, rowptr, csr_src, csr_coef,
                                              b2, batch, pooled);

    k_head<<<GG, 64, 0, stream>>>(pooled, cnt, lin1w, lin1b, lin2w, lin2b, out);
}

// Round 3
// 428.037 us; speedup vs baseline: 1.8319x; 1.1951x over previous
//
#include <hip/hip_runtime.h>
#include <math.h>

#define NN 50000
#define EE 800000
#define HH 64
#define GG 512
#define SCAN_NB ((NN + 1023) / 1024)   // 49 blocks

// ---------------- degree / norm ----------------

__global__ void k_deg(const int* __restrict__ dst, int* __restrict__ deg) {
    int e = blockIdx.x * blockDim.x + threadIdx.x;
    if (e < EE) atomicAdd(&deg[dst[e]], 1);
}

__global__ void k_dinv(const int* __restrict__ deg, float* __restrict__ dinv) {
    int i = blockIdx.x * blockDim.x + threadIdx.x;
    if (i < NN) dinv[i] = 1.0f / sqrtf((float)(deg[i] + 1));  // +1 self-loop
}

// ---------------- 3-phase parallel exclusive scan: deg -> rowptr ----------------

__global__ void __launch_bounds__(1024) k_scan1(const int* __restrict__ deg,
                                                int* __restrict__ rowptr,
                                                int* __restrict__ bsum) {
    int tid = threadIdx.x;
    int lane = tid & 63, w = tid >> 6;
    int i = blockIdx.x * 1024 + tid;
    int v = (i < NN) ? deg[i] : 0;
    int x = v;                                   // inclusive wave scan
#pragma unroll
    for (int off = 1; off < 64; off <<= 1) {
        int y = __shfl_up(x, off);
        if (lane >= off) x += y;
    }
    __shared__ int ws[16];
    if (lane == 63) ws[w] = x;
    __syncthreads();
    if (tid < 16) {
        int y = ws[tid];
        int z = y;
#pragma unroll
        for (int off = 1; off < 16; off <<= 1) {
            int t2 = __shfl_up(z, off);
            if (tid >= off) z += t2;
        }
        ws[tid] = z - y;                          // exclusive wave offsets
    }
    __syncthreads();
    int excl = x - v + ws[w];
    if (i < NN) rowptr[i] = excl;
    if (tid == 1023) bsum[blockIdx.x] = excl + v; // block total
}

__global__ void __launch_bounds__(64) k_scan2(int* __restrict__ bsum) {
    int lane = threadIdx.x;
    int v = (lane < SCAN_NB) ? bsum[lane] : 0;
    int x = v;
#pragma unroll
    for (int off = 1; off < 64; off <<= 1) {
        int y = __shfl_up(x, off);
        if (lane >= off) x += y;
    }
    if (lane < SCAN_NB) bsum[lane] = x - v;       // exclusive block offsets
}

__global__ void __launch_bounds__(1024) k_scan3(int* __restrict__ rowptr,
                                                const int* __restrict__ bsum) {
    int i = blockIdx.x * 1024 + threadIdx.x;
    if (i < NN) rowptr[i] += bsum[blockIdx.x];
    if (i == 0) rowptr[NN] = EE;
}

// ---------------- CSR fill: per-edge slot by atomic cursor ----------------

__global__ void k_fill(const int* __restrict__ src, const int* __restrict__ dst,
                       const float* __restrict__ dinv, const int* __restrict__ rowptr,
                       int* __restrict__ cursor, int* __restrict__ csr_src,
                       float* __restrict__ csr_coef) {
    int e = blockIdx.x * blockDim.x + threadIdx.x;
    if (e >= EE) return;
    int s = src[e], d = dst[e];
    int pos = atomicAdd(&cursor[d], 1);
    int o = rowptr[d] + pos;
    csr_src[o] = s;
    csr_coef[o] = dinv[s] * dinv[d];
}

// ---------------- dense transform: t = act(x) @ W ----------------

template<bool RELU>
__global__ void __launch_bounds__(256) k_xform(const float* __restrict__ x,
                                               const float* __restrict__ W,
                                               float* __restrict__ t) {
    __shared__ float sW[64 * 64];   // 16 KB
    __shared__ float sX[32 * 65];   // padded
    int tid = threadIdx.x;
    for (int k = tid; k < 64 * 64; k += 256) sW[k] = W[k];
    int row0 = blockIdx.x * 32;
    for (int v = tid; v < 32 * 16; v += 256) {
        int r  = v >> 4;
        int k4 = (v & 15) * 4;
        int row = row0 + r;
        float4 val = make_float4(0.f, 0.f, 0.f, 0.f);
        if (row < NN) val = *(const float4*)(x + (size_t)row * 64 + k4);
        if (RELU) {
            val.x = fmaxf(val.x, 0.f); val.y = fmaxf(val.y, 0.f);
            val.z = fmaxf(val.z, 0.f); val.w = fmaxf(val.w, 0.f);
        }
        sX[r * 65 + k4 + 0] = val.x;
        sX[r * 65 + k4 + 1] = val.y;
        sX[r * 65 + k4 + 2] = val.z;
        sX[r * 65 + k4 + 3] = val.w;
    }
    __syncthreads();
    int r  = tid >> 3;        // 0..31
    int c0 = (tid & 7) * 8;   // 0,8,...,56
    float acc[8] = {0.f, 0.f, 0.f, 0.f, 0.f, 0.f, 0.f, 0.f};
    for (int k = 0; k < 64; ++k) {
        float xv = sX[r * 65 + k];
#pragma unroll
        for (int j = 0; j < 8; ++j) acc[j] = fmaf(xv, sW[k * 64 + c0 + j], acc[j]);
    }
    int row = row0 + r;
    if (row < NN) {
        float4* o = (float4*)(t + (size_t)row * 64 + c0);
        o[0] = make_float4(acc[0], acc[1], acc[2], acc[3]);
        o[1] = make_float4(acc[4], acc[5], acc[6], acc[7]);
    }
}

// ---------------- CSR gather: one wave per node, fused self-loop + bias ----------------

template<bool POOL>
__global__ void __launch_bounds__(256) k_gather(const float* __restrict__ t,
                                                const float* __restrict__ dinv,
                                                const int* __restrict__ rowptr,
                                                const int* __restrict__ csr_src,
                                                const float* __restrict__ csr_coef,
                                                const float* __restrict__ b,
                                                const int* __restrict__ batch,
                                                float* __restrict__ out) {
    int wave = (blockIdx.x * blockDim.x + threadIdx.x) >> 6;
    int c = threadIdx.x & 63;
    if (wave >= NN) return;
    int i = wave;
    float dv = dinv[i];
    float acc = fmaf(t[(size_t)i * 64 + c], dv * dv, b[c]);
    float acc2 = 0.0f;
    int e = rowptr[i], end = rowptr[i + 1];
    for (; e + 1 < end; e += 2) {
        int   s0 = csr_src[e],     s1 = csr_src[e + 1];
        float f0 = csr_coef[e],    f1 = csr_coef[e + 1];
        acc  = fmaf(t[(size_t)s0 * 64 + c], f0, acc);
        acc2 = fmaf(t[(size_t)s1 * 64 + c], f1, acc2);
    }
    if (e < end) acc = fmaf(t[(size_t)csr_src[e] * 64 + c], csr_coef[e], acc);
    acc += acc2;
    if (POOL) {
        atomicAdd(&out[(size_t)batch[i] * 64 + c], fmaxf(acc, 0.0f));
    } else {
        out[(size_t)i * 64 + c] = acc;
    }
}

__global__ void k_cnt(const int* __restrict__ batch, int* __restrict__ cnt) {
    int i = blockIdx.x * blockDim.x + threadIdx.x;
    if (i < NN) atomicAdd(&cnt[batch[i]], 1);
}

// ---------------- head: per-graph MLP, one wave per graph ----------------

__global__ void __launch_bounds__(64) k_head(const float* __restrict__ pooled,
                                             const int* __restrict__ cnt,
                                             const float* __restrict__ w1,
                                             const float* __restrict__ b1,
                                             const float* __restrict__ w2,
                                             const float* __restrict__ b2,
                                             float* __restrict__ out) {
    int g = blockIdx.x;
    int c = threadIdx.x;
    __shared__ float sp[64];
    float cf = fmaxf((float)cnt[g], 1.0f);
    sp[c] = pooled[(size_t)g * 64 + c] / cf;
    __syncthreads();
    float acc = b1[c];
    for (int k = 0; k < 64; ++k) acc = fmaf(sp[k], w1[k * 64 + c], acc);
    float h1 = fmaxf(acc, 0.0f);
    float p = h1 * w2[c];
#pragma unroll
    for (int off = 32; off > 0; off >>= 1) p += __shfl_down(p, off);
    if (c == 0) out[g] = p + b2[0];
}

// ---------------- launch ----------------

extern "C" void kernel_launch(void* const* d_in, const int* in_sizes, int n_in,
                              void* d_out, int out_size, void* d_ws, size_t ws_size,
                              hipStream_t stream) {
    const float* x      = (const float*)d_in[0];
    const int*   ei     = (const int*)d_in[1];
    const int*   batch  = (const int*)d_in[2];
    const float* W0     = (const float*)d_in[3];
    const float* b0     = (const float*)d_in[4];
    const float* W1     = (const float*)d_in[5];
    const float* b1     = (const float*)d_in[6];
    const float* W2     = (const float*)d_in[7];
    const float* b2     = (const float*)d_in[8];
    const float* lin1w  = (const float*)d_in[9];
    const float* lin1b  = (const float*)d_in[10];
    const float* lin2w  = (const float*)d_in[11];
    const float* lin2b  = (const float*)d_in[12];
    float* out = (float*)d_out;

    const int* src = ei;
    const int* dst = ei + EE;

    char* ws = (char*)d_ws;
    size_t off = 0;
    auto carve = [&](size_t bytes) {
        void* p = ws + off;
        off = (off + bytes + 255) & ~(size_t)255;
        return p;
    };
    int*   deg      = (int*)carve((size_t)NN * 4);
    float* dinv     = (float*)carve((size_t)NN * 4);
    int*   rowptr   = (int*)carve((size_t)(NN + 1) * 4);
    int*   cursor   = (int*)carve((size_t)NN * 4);
    int*   bsum     = (int*)carve((size_t)SCAN_NB * 4);
    int*   csr_src  = (int*)carve((size_t)EE * 4);
    float* csr_coef = (float*)carve((size_t)EE * 4);
    float* bufT     = (float*)carve((size_t)NN * 64 * 4);
    float* bufA     = (float*)carve((size_t)NN * 64 * 4);
    float* pooled   = (float*)carve((size_t)GG * 64 * 4);
    int*   cnt      = (int*)carve((size_t)GG * 4);

    hipMemsetAsync(deg, 0, (size_t)NN * 4, stream);
    hipMemsetAsync(cursor, 0, (size_t)NN * 4, stream);
    hipMemsetAsync(pooled, 0, (size_t)GG * 64 * 4, stream);
    hipMemsetAsync(cnt, 0, (size_t)GG * 4, stream);

    // ---- CSR build ----
    k_deg  <<<(EE + 255) / 256, 256, 0, stream>>>(dst, deg);
    k_dinv <<<(NN + 255) / 256, 256, 0, stream>>>(deg, dinv);
    k_scan1<<<SCAN_NB, 1024, 0, stream>>>(deg, rowptr, bsum);
    k_scan2<<<1, 64, 0, stream>>>(bsum);
    k_scan3<<<SCAN_NB, 1024, 0, stream>>>(rowptr, bsum);
    k_fill <<<(EE + 255) / 256, 256, 0, stream>>>(src, dst, dinv, rowptr, cursor,
                                                  csr_src, csr_coef);
    k_cnt  <<<(NN + 255) / 256, 256, 0, stream>>>(batch, cnt);

    const int xgrid = (NN + 31) / 32;
    const int ggrid = (NN * 64 + 255) / 256;   // one 64-lane wave per node

    // layer 0: x -> bufA
    k_xform<false><<<xgrid, 256, 0, stream>>>(x, W0, bufT);
    k_gather<false><<<ggrid, 256, 0, stream>>>(bufT, dinv, rowptr, csr_src, csr_coef,
                                               b0, batch, bufA);
    // layer 1
    k_xform<true><<<xgrid, 256, 0, stream>>>(bufA, W1, bufT);
    k_gather<false><<<ggrid, 256, 0, stream>>>(bufT, dinv, rowptr, csr_src, csr_coef,
                                               b1, batch, bufA);
    // layer 2: relu + mean-pool fused into gather
    k_xform<true><<<xgrid, 256, 0, stream>>>(bufA, W2, bufT);
    k_gather<true><<<ggrid, 256, 0, stream>>>(bufT, dinv, rowptr, csr_src, csr_coef,
                                              b2, batch, pooled);

    k_head<<<GG, 64, 0, stream>>>(pooled, cnt, lin1w, lin1b, lin2w, lin2b, out);
}

// Round 4
// 356.513 us; speedup vs baseline: 2.1994x; 1.2006x over previous
//
#include <hip/hip_runtime.h>
#include <math.h>

#define NN 50000
#define EE 800000
#define HH 64
#define GG 512
#define SCAN_NB ((NN + 1023) / 1024)   // 49 blocks

// ---------------- degree ----------------

__global__ void k_deg(const int* __restrict__ dst, int* __restrict__ deg) {
    int e = blockIdx.x * blockDim.x + threadIdx.x;
    if (e < EE) atomicAdd(&deg[dst[e]], 1);
}

// ---------------- 3-phase parallel exclusive scan: deg -> rowptr (+ dinv fused) ----------------

__global__ void __launch_bounds__(1024) k_scan1(const int* __restrict__ deg,
                                                int* __restrict__ rowptr,
                                                int* __restrict__ bsum,
                                                float* __restrict__ dinv) {
    int tid = threadIdx.x;
    int lane = tid & 63, w = tid >> 6;
    int i = blockIdx.x * 1024 + tid;
    int v = (i < NN) ? deg[i] : 0;
    if (i < NN) dinv[i] = 1.0f / sqrtf((float)(v + 1));   // +1 self-loop
    int x = v;                                    // inclusive wave scan
#pragma unroll
    for (int off = 1; off < 64; off <<= 1) {
        int y = __shfl_up(x, off);
        if (lane >= off) x += y;
    }
    __shared__ int ws[16];
    if (lane == 63) ws[w] = x;
    __syncthreads();
    if (tid < 16) {
        int y = ws[tid];
        int z = y;
#pragma unroll
        for (int off = 1; off < 16; off <<= 1) {
            int t2 = __shfl_up(z, off);
            if (tid >= off) z += t2;
        }
        ws[tid] = z - y;                          // exclusive wave offsets
    }
    __syncthreads();
    int excl = x - v + ws[w];
    if (i < NN) rowptr[i] = excl;
    if (tid == 1023) bsum[blockIdx.x] = excl + v; // block total
}

__global__ void __launch_bounds__(64) k_scan2(int* __restrict__ bsum) {
    int lane = threadIdx.x;
    int v = (lane < SCAN_NB) ? bsum[lane] : 0;
    int x = v;
#pragma unroll
    for (int off = 1; off < 64; off <<= 1) {
        int y = __shfl_up(x, off);
        if (lane >= off) x += y;
    }
    if (lane < SCAN_NB) bsum[lane] = x - v;       // exclusive block offsets
}

__global__ void __launch_bounds__(1024) k_scan3(int* __restrict__ rowptr,
                                                const int* __restrict__ bsum) {
    int i = blockIdx.x * 1024 + threadIdx.x;
    if (i < NN) rowptr[i] += bsum[blockIdx.x];
    if (i == 0) rowptr[NN] = EE;
}

// ---------------- CSR fill (src only; coef folded into t-rows) ----------------

__global__ void k_fill(const int* __restrict__ src, const int* __restrict__ dst,
                       const int* __restrict__ rowptr,
                       int* __restrict__ cursor, int* __restrict__ csr_src) {
    int e = blockIdx.x * blockDim.x + threadIdx.x;
    if (e >= EE) return;
    int d = dst[e];
    int pos = atomicAdd(&cursor[d], 1);
    csr_src[rowptr[d] + pos] = src[e];
}

// ---------------- dense transform: t' = (act(x) @ W) * dinv[row] ----------------

template<bool RELU>
__global__ void __launch_bounds__(256) k_xform(const float* __restrict__ x,
                                               const float* __restrict__ W,
                                               const float* __restrict__ dinv,
                                               float* __restrict__ t) {
    __shared__ float sW[64 * 64];   // 16 KB
    __shared__ float sX[32 * 65];   // padded
    int tid = threadIdx.x;
    for (int k = tid; k < 64 * 64; k += 256) sW[k] = W[k];
    int row0 = blockIdx.x * 32;
    for (int v = tid; v < 32 * 16; v += 256) {
        int r  = v >> 4;
        int k4 = (v & 15) * 4;
        int row = row0 + r;
        float4 val = make_float4(0.f, 0.f, 0.f, 0.f);
        if (row < NN) val = *(const float4*)(x + (size_t)row * 64 + k4);
        if (RELU) {
            val.x = fmaxf(val.x, 0.f); val.y = fmaxf(val.y, 0.f);
            val.z = fmaxf(val.z, 0.f); val.w = fmaxf(val.w, 0.f);
        }
        sX[r * 65 + k4 + 0] = val.x;
        sX[r * 65 + k4 + 1] = val.y;
        sX[r * 65 + k4 + 2] = val.z;
        sX[r * 65 + k4 + 3] = val.w;
    }
    __syncthreads();
    int r  = tid >> 3;        // 0..31
    int c0 = (tid & 7) * 8;   // 0,8,...,56
    float acc[8] = {0.f, 0.f, 0.f, 0.f, 0.f, 0.f, 0.f, 0.f};
    for (int k = 0; k < 64; ++k) {
        float xv = sX[r * 65 + k];
#pragma unroll
        for (int j = 0; j < 8; ++j) acc[j] = fmaf(xv, sW[k * 64 + c0 + j], acc[j]);
    }
    int row = row0 + r;
    if (row < NN) {
        float dv = dinv[row];
#pragma unroll
        for (int j = 0; j < 8; ++j) acc[j] *= dv;
        float4* o = (float4*)(t + (size_t)row * 64 + c0);
        o[0] = make_float4(acc[0], acc[1], acc[2], acc[3]);
        o[1] = make_float4(acc[4], acc[5], acc[6], acc[7]);
    }
}

// ---------------- CSR gather: one wave per node, 8-deep batched gathers ----------------
// out[i] = dinv[i] * (t'[i] + sum_{s in N(i)} t'[s]) + b

template<bool POOL>
__global__ void __launch_bounds__(256) k_gather(const float* __restrict__ t,
                                                const float* __restrict__ dinv,
                                                const int* __restrict__ rowptr,
                                                const int* __restrict__ csr_src,
                                                const float* __restrict__ b,
                                                const int* __restrict__ batch,
                                                float* __restrict__ out) {
    int i = (blockIdx.x * blockDim.x + threadIdx.x) >> 6;
    int c = threadIdx.x & 63;
    if (i >= NN) return;
    float acc = t[(size_t)i * 64 + c];            // self-loop (t' already *dinv[i])
    float a0 = 0.f, a1 = 0.f, a2 = 0.f, a3 = 0.f;
    int e = rowptr[i], end = rowptr[i + 1];
    for (; e + 8 <= end; e += 8) {
        int s0 = csr_src[e + 0], s1 = csr_src[e + 1];
        int s2 = csr_src[e + 2], s3 = csr_src[e + 3];
        int s4 = csr_src[e + 4], s5 = csr_src[e + 5];
        int s6 = csr_src[e + 6], s7 = csr_src[e + 7];
        float v0 = t[(size_t)s0 * 64 + c], v1 = t[(size_t)s1 * 64 + c];
        float v2 = t[(size_t)s2 * 64 + c], v3 = t[(size_t)s3 * 64 + c];
        float v4 = t[(size_t)s4 * 64 + c], v5 = t[(size_t)s5 * 64 + c];
        float v6 = t[(size_t)s6 * 64 + c], v7 = t[(size_t)s7 * 64 + c];
        a0 += v0 + v4; a1 += v1 + v5; a2 += v2 + v6; a3 += v3 + v7;
    }
    if (e + 4 <= end) {
        int s0 = csr_src[e + 0], s1 = csr_src[e + 1];
        int s2 = csr_src[e + 2], s3 = csr_src[e + 3];
        a0 += t[(size_t)s0 * 64 + c]; a1 += t[(size_t)s1 * 64 + c];
        a2 += t[(size_t)s2 * 64 + c]; a3 += t[(size_t)s3 * 64 + c];
        e += 4;
    }
    for (; e < end; ++e) a0 += t[(size_t)csr_src[e] * 64 + c];
    acc += (a0 + a1) + (a2 + a3);
    float r = fmaf(acc, dinv[i], b[c]);
    if (POOL) {
        atomicAdd(&out[(size_t)batch[i] * 64 + c], fmaxf(r, 0.0f));
    } else {
        out[(size_t)i * 64 + c] = r;
    }
}

__global__ void k_cnt(const int* __restrict__ batch, int* __restrict__ cnt) {
    int i = blockIdx.x * blockDim.x + threadIdx.x;
    if (i < NN) atomicAdd(&cnt[batch[i]], 1);
}

// ---------------- head: per-graph MLP, one wave per graph ----------------

__global__ void __launch_bounds__(64) k_head(const float* __restrict__ pooled,
                                             const int* __restrict__ cnt,
                                             const float* __restrict__ w1,
                                             const float* __restrict__ b1,
                                             const float* __restrict__ w2,
                                             const float* __restrict__ b2,
                                             float* __restrict__ out) {
    int g = blockIdx.x;
    int c = threadIdx.x;
    __shared__ float sp[64];
    float cf = fmaxf((float)cnt[g], 1.0f);
    sp[c] = pooled[(size_t)g * 64 + c] / cf;
    __syncthreads();
    float acc = b1[c];
    for (int k = 0; k < 64; ++k) acc = fmaf(sp[k], w1[k * 64 + c], acc);
    float h1 = fmaxf(acc, 0.0f);
    float p = h1 * w2[c];
#pragma unroll
    for (int off = 32; off > 0; off >>= 1) p += __shfl_down(p, off);
    if (c == 0) out[g] = p + b2[0];
}

// ---------------- launch ----------------

extern "C" void kernel_launch(void* const* d_in, const int* in_sizes, int n_in,
                              void* d_out, int out_size, void* d_ws, size_t ws_size,
                              hipStream_t stream) {
    const float* x      = (const float*)d_in[0];
    const int*   ei     = (const int*)d_in[1];
    const int*   batch  = (const int*)d_in[2];
    const float* W0     = (const float*)d_in[3];
    const float* b0     = (const float*)d_in[4];
    const float* W1     = (const float*)d_in[5];
    const float* b1     = (const float*)d_in[6];
    const float* W2     = (const float*)d_in[7];
    const float* b2     = (const float*)d_in[8];
    const float* lin1w  = (const float*)d_in[9];
    const float* lin1b  = (const float*)d_in[10];
    const float* lin2w  = (const float*)d_in[11];
    const float* lin2b  = (const float*)d_in[12];
    float* out = (float*)d_out;

    const int* src = ei;
    const int* dst = ei + EE;

    char* ws = (char*)d_ws;
    size_t off = 0;
    auto carve = [&](size_t bytes) {
        void* p = ws + off;
        off = (off + bytes + 255) & ~(size_t)255;
        return p;
    };
    // zero-initialized group first (single memset covers [0, zero_span))
    int*   deg      = (int*)carve((size_t)NN * 4);
    int*   cursor   = (int*)carve((size_t)NN * 4);
    float* pooled   = (float*)carve((size_t)GG * 64 * 4);
    int*   cnt      = (int*)carve((size_t)GG * 4);
    size_t zero_span = off;
    float* dinv     = (float*)carve((size_t)NN * 4);
    int*   rowptr   = (int*)carve((size_t)(NN + 1) * 4);
    int*   bsum     = (int*)carve((size_t)SCAN_NB * 4);
    int*   csr_src  = (int*)carve((size_t)EE * 4);
    float* bufT     = (float*)carve((size_t)NN * 64 * 4);
    float* bufA     = (float*)carve((size_t)NN * 64 * 4);

    hipMemsetAsync(deg, 0, zero_span, stream);

    // ---- CSR build ----
    k_deg  <<<(EE + 255) / 256, 256, 0, stream>>>(dst, deg);
    k_scan1<<<SCAN_NB, 1024, 0, stream>>>(deg, rowptr, bsum, dinv);
    k_scan2<<<1, 64, 0, stream>>>(bsum);
    k_scan3<<<SCAN_NB, 1024, 0, stream>>>(rowptr, bsum);
    k_fill <<<(EE + 255) / 256, 256, 0, stream>>>(src, dst, rowptr, cursor, csr_src);
    k_cnt  <<<(NN + 255) / 256, 256, 0, stream>>>(batch, cnt);

    const int xgrid = (NN + 31) / 32;
    const int ggrid = (NN * 64 + 255) / 256;   // one 64-lane wave per node

    // layer 0: x -> bufA
    k_xform<false><<<xgrid, 256, 0, stream>>>(x, W0, dinv, bufT);
    k_gather<false><<<ggrid, 256, 0, stream>>>(bufT, dinv, rowptr, csr_src,
                                               b0, batch, bufA);
    // layer 1
    k_xform<true><<<xgrid, 256, 0, stream>>>(bufA, W1, dinv, bufT);
    k_gather<false><<<ggrid, 256, 0, stream>>>(bufT, dinv, rowptr, csr_src,
                                               b1, batch, bufA);
    // layer 2: relu + mean-pool fused into gather
    k_xform<true><<<xgrid, 256, 0, stream>>>(bufA, W2, dinv, bufT);
    k_gather<true><<<ggrid, 256, 0, stream>>>(bufT, dinv, rowptr, csr_src,
                                              b2, batch, pooled);

    k_head<<<GG, 64, 0, stream>>>(pooled, cnt, lin1w, lin1b, lin2w, lin2b, out);
}

// Round 5
// 341.501 us; speedup vs baseline: 2.2961x; 1.0440x over previous
//
#include <hip/hip_runtime.h>
#include <math.h>

#define NN 50000
#define EE 800000
#define HH 64
#define GG 512
#define SCAN_NB ((NN + 1023) / 1024)       // 49 blocks (covers NN+1 entries: 49*1024=50176)
#define PE (EE + 7 * NN)                   // padded CSR capacity

// ---------------- degree ----------------

__global__ void k_deg(const int* __restrict__ dst, int* __restrict__ deg) {
    int e = blockIdx.x * blockDim.x + threadIdx.x;
    if (e < EE) atomicAdd(&deg[dst[e]], 1);
}

// ---------------- scan over PADDED degrees -> local rowptr + block sums (+ dinv) ----------------
// rowptr[i] holds block-local exclusive prefix of pdeg; consumers add bsum[i>>10].

__global__ void __launch_bounds__(1024) k_scan1(const int* __restrict__ deg,
                                                int* __restrict__ rowptr,
                                                int* __restrict__ bsum,
                                                float* __restrict__ dinv) {
    int tid = threadIdx.x;
    int lane = tid & 63, w = tid >> 6;
    int i = blockIdx.x * 1024 + tid;
    int d = (i < NN) ? deg[i] : 0;
    if (i < NN)       dinv[i] = 1.0f / sqrtf((float)(d + 1));   // +1 self-loop
    else if (i == NN) dinv[i] = 0.0f;                           // zero row
    int v = (i < NN) ? ((d + 7) & ~7) : 0;                      // padded degree
    int x = v;                                                  // inclusive wave scan
#pragma unroll
    for (int off = 1; off < 64; off <<= 1) {
        int y = __shfl_up(x, off);
        if (lane >= off) x += y;
    }
    __shared__ int ws[16];
    if (lane == 63) ws[w] = x;
    __syncthreads();
    if (tid < 16) {
        int y = ws[tid];
        int z = y;
#pragma unroll
        for (int off = 1; off < 16; off <<= 1) {
            int t2 = __shfl_up(z, off);
            if (tid >= off) z += t2;
        }
        ws[tid] = z - y;                          // exclusive wave offsets
    }
    __syncthreads();
    int excl = x - v + ws[w];
    if (i <= NN) rowptr[i] = excl;                // local exclusive prefix
    if (tid == 1023) bsum[blockIdx.x] = excl + v; // block total
}

__global__ void __launch_bounds__(64) k_scan2(int* __restrict__ bsum) {
    int lane = threadIdx.x;
    int v = (lane < SCAN_NB) ? bsum[lane] : 0;
    int x = v;
#pragma unroll
    for (int off = 1; off < 64; off <<= 1) {
        int y = __shfl_up(x, off);
        if (lane >= off) x += y;
    }
    if (lane < SCAN_NB) bsum[lane] = x - v;       // exclusive block offsets
}

// ---------------- CSR fill: edges + dummy padding + per-graph counts (3 segments) ----------------

__global__ void k_fill(const int* __restrict__ src, const int* __restrict__ dst,
                       const int* __restrict__ rowptr, const int* __restrict__ bsum,
                       const int* __restrict__ deg, const int* __restrict__ batch,
                       int* __restrict__ cursor, int* __restrict__ csr_src,
                       int* __restrict__ cnt) {
    int tid = blockIdx.x * blockDim.x + threadIdx.x;
    if (tid < EE) {
        int d = dst[tid];
        int pos = atomicAdd(&cursor[d], 1);
        csr_src[rowptr[d] + bsum[d >> 10] + pos] = src[tid];
    } else if (tid < EE + NN) {
        int i = tid - EE;
        int dg = deg[i];
        int start = rowptr[i] + bsum[i >> 10] + dg;
        int pad = ((dg + 7) & ~7) - dg;
        for (int j = 0; j < pad; ++j) csr_src[start + j] = NN;   // dummy -> zero row
    } else if (tid < EE + 2 * NN) {
        atomicAdd(&cnt[batch[tid - EE - NN]], 1);
    }
}

// ---------------- dense transform: t' = (act(x) @ W) * dinv[row]; row NN zeroed ----------------

template<bool RELU>
__global__ void __launch_bounds__(256) k_xform(const float* __restrict__ x,
                                               const float* __restrict__ W,
                                               const float* __restrict__ dinv,
                                               float* __restrict__ t) {
    __shared__ float sW[64 * 64];   // 16 KB
    __shared__ float sX[32 * 65];   // padded
    int tid = threadIdx.x;
    for (int k = tid; k < 64 * 64; k += 256) sW[k] = W[k];
    int row0 = blockIdx.x * 32;
    for (int v = tid; v < 32 * 16; v += 256) {
        int r  = v >> 4;
        int k4 = (v & 15) * 4;
        int row = row0 + r;
        float4 val = make_float4(0.f, 0.f, 0.f, 0.f);
        if (row < NN) val = *(const float4*)(x + (size_t)row * 64 + k4);
        if (RELU) {
            val.x = fmaxf(val.x, 0.f); val.y = fmaxf(val.y, 0.f);
            val.z = fmaxf(val.z, 0.f); val.w = fmaxf(val.w, 0.f);
        }
        sX[r * 65 + k4 + 0] = val.x;
        sX[r * 65 + k4 + 1] = val.y;
        sX[r * 65 + k4 + 2] = val.z;
        sX[r * 65 + k4 + 3] = val.w;
    }
    __syncthreads();
    int r  = tid >> 3;        // 0..31
    int c0 = (tid & 7) * 8;   // 0,8,...,56
    float acc[8] = {0.f, 0.f, 0.f, 0.f, 0.f, 0.f, 0.f, 0.f};
    for (int k = 0; k < 64; ++k) {
        float xv = sX[r * 65 + k];
#pragma unroll
        for (int j = 0; j < 8; ++j) acc[j] = fmaf(xv, sW[k * 64 + c0 + j], acc[j]);
    }
    int row = row0 + r;
    if (row <= NN) {          // row NN: acc==0 -> writes zero row
        float dv = dinv[row];
#pragma unroll
        for (int j = 0; j < 8; ++j) acc[j] *= dv;
        float4* o = (float4*)(t + (size_t)row * 64 + c0);
        o[0] = make_float4(acc[0], acc[1], acc[2], acc[3]);
        o[1] = make_float4(acc[4], acc[5], acc[6], acc[7]);
    }
}

// ---------------- CSR gather: one wave per node, padded 8-deep batches, scalar idx loads ----
// out[i] = dinv[i] * (t'[i] + sum_{s in N(i)} t'[s]) + b

template<bool POOL>
__global__ void __launch_bounds__(256) k_gather(const float* __restrict__ t,
                                                const float* __restrict__ dinv,
                                                const int* __restrict__ rowptr,
                                                const int* __restrict__ bsum,
                                                const int* __restrict__ csr_src,
                                                const float* __restrict__ b,
                                                const int* __restrict__ batch,
                                                float* __restrict__ out) {
    int i = __builtin_amdgcn_readfirstlane((blockIdx.x * blockDim.x + threadIdx.x) >> 6);
    int c = threadIdx.x & 63;
    if (i >= NN) return;
    int e   = __builtin_amdgcn_readfirstlane(rowptr[i]     + bsum[i >> 10]);
    int end = __builtin_amdgcn_readfirstlane(rowptr[i + 1] + bsum[(i + 1) >> 10]);
    float acc = t[(size_t)i * 64 + c];            // self-loop (t' already *dinv[i])
    float a0 = 0.f, a1 = 0.f, a2 = 0.f, a3 = 0.f;
    for (; e < end; e += 8) {                     // rows padded to x8: no tails
        int s0 = csr_src[e + 0], s1 = csr_src[e + 1];
        int s2 = csr_src[e + 2], s3 = csr_src[e + 3];
        int s4 = csr_src[e + 4], s5 = csr_src[e + 5];
        int s6 = csr_src[e + 6], s7 = csr_src[e + 7];
        float v0 = t[(size_t)s0 * 64 + c], v1 = t[(size_t)s1 * 64 + c];
        float v2 = t[(size_t)s2 * 64 + c], v3 = t[(size_t)s3 * 64 + c];
        float v4 = t[(size_t)s4 * 64 + c], v5 = t[(size_t)s5 * 64 + c];
        float v6 = t[(size_t)s6 * 64 + c], v7 = t[(size_t)s7 * 64 + c];
        a0 += v0 + v4; a1 += v1 + v5; a2 += v2 + v6; a3 += v3 + v7;
    }
    acc += (a0 + a1) + (a2 + a3);
    float r = fmaf(acc, dinv[i], b[c]);
    if (POOL) {
        atomicAdd(&out[(size_t)batch[i] * 64 + c], fmaxf(r, 0.0f));
    } else {
        out[(size_t)i * 64 + c] = r;
    }
}

// ---------------- head: per-graph MLP, one wave per graph ----------------

__global__ void __launch_bounds__(64) k_head(const float* __restrict__ pooled,
                                             const int* __restrict__ cnt,
                                             const float* __restrict__ w1,
                                             const float* __restrict__ b1,
                                             const float* __restrict__ w2,
                                             const float* __restrict__ b2,
                                             float* __restrict__ out) {
    int g = blockIdx.x;
    int c = threadIdx.x;
    __shared__ float sp[64];
    float cf = fmaxf((float)cnt[g], 1.0f);
    sp[c] = pooled[(size_t)g * 64 + c] / cf;
    __syncthreads();
    float acc = b1[c];
    for (int k = 0; k < 64; ++k) acc = fmaf(sp[k], w1[k * 64 + c], acc);
    float h1 = fmaxf(acc, 0.0f);
    float p = h1 * w2[c];
#pragma unroll
    for (int off = 32; off > 0; off >>= 1) p += __shfl_down(p, off);
    if (c == 0) out[g] = p + b2[0];
}

// ---------------- launch ----------------

extern "C" void kernel_launch(void* const* d_in, const int* in_sizes, int n_in,
                              void* d_out, int out_size, void* d_ws, size_t ws_size,
                              hipStream_t stream) {
    const float* x      = (const float*)d_in[0];
    const int*   ei     = (const int*)d_in[1];
    const int*   batch  = (const int*)d_in[2];
    const float* W0     = (const float*)d_in[3];
    const float* b0     = (const float*)d_in[4];
    const float* W1     = (const float*)d_in[5];
    const float* b1     = (const float*)d_in[6];
    const float* W2     = (const float*)d_in[7];
    const float* b2     = (const float*)d_in[8];
    const float* lin1w  = (const float*)d_in[9];
    const float* lin1b  = (const float*)d_in[10];
    const float* lin2w  = (const float*)d_in[11];
    const float* lin2b  = (const float*)d_in[12];
    float* out = (float*)d_out;

    const int* src = ei;
    const int* dst = ei + EE;

    char* ws = (char*)d_ws;
    size_t off = 0;
    auto carve = [&](size_t bytes) {
        void* p = ws + off;
        off = (off + bytes + 255) & ~(size_t)255;
        return p;
    };
    // zero-initialized group first (single memset covers [0, zero_span))
    int*   deg      = (int*)carve((size_t)NN * 4);
    int*   cursor   = (int*)carve((size_t)NN * 4);
    float* pooled   = (float*)carve((size_t)GG * 64 * 4);
    int*   cnt      = (int*)carve((size_t)GG * 4);
    size_t zero_span = off;
    float* dinv     = (float*)carve((size_t)(NN + 1) * 4);
    int*   rowptr   = (int*)carve((size_t)(NN + 1) * 4);
    int*   bsum     = (int*)carve((size_t)SCAN_NB * 4);
    int*   csr_src  = (int*)carve((size_t)PE * 4);
    float* bufT     = (float*)carve((size_t)(NN + 1) * 64 * 4);  // +1 zero row
    float* bufA     = (float*)carve((size_t)NN * 64 * 4);

    hipMemsetAsync(deg, 0, zero_span, stream);

    // ---- CSR build ----
    k_deg  <<<(EE + 255) / 256, 256, 0, stream>>>(dst, deg);
    k_scan1<<<SCAN_NB, 1024, 0, stream>>>(deg, rowptr, bsum, dinv);
    k_scan2<<<1, 64, 0, stream>>>(bsum);
    k_fill <<<(EE + 2 * NN + 255) / 256, 256, 0, stream>>>(src, dst, rowptr, bsum,
                                                           deg, batch, cursor,
                                                           csr_src, cnt);

    const int xgrid = (NN + 1 + 31) / 32;        // includes zero row NN
    const int ggrid = (NN * 64) / 256;           // one 64-lane wave per node

    // layer 0: x -> bufA
    k_xform<false><<<xgrid, 256, 0, stream>>>(x, W0, dinv, bufT);
    k_gather<false><<<ggrid, 256, 0, stream>>>(bufT, dinv, rowptr, bsum, csr_src,
                                               b0, batch, bufA);
    // layer 1
    k_xform<true><<<xgrid, 256, 0, stream>>>(bufA, W1, dinv, bufT);
    k_gather<false><<<ggrid, 256, 0, stream>>>(bufT, dinv, rowptr, bsum, csr_src,
                                               b1, batch, bufA);
    // layer 2: relu + mean-pool fused into gather
    k_xform<true><<<xgrid, 256, 0, stream>>>(bufA, W2, dinv, bufT);
    k_gather<true><<<ggrid, 256, 0, stream>>>(bufT, dinv, rowptr, bsum, csr_src,
                                              b2, batch, pooled);

    k_head<<<GG, 64, 0, stream>>>(pooled, cnt, lin1w, lin1b, lin2w, lin2b, out);
}

// Round 9
// 316.711 us; speedup vs baseline: 2.4758x; 1.0783x over previous
//
#include <hip/hip_runtime.h>
#include <math.h>

#define NN 50000
#define EE 800000
#define HH 64
#define GG 512
#define SCAN_NB ((NN + 1023) / 1024)       // 49 blocks (covers NN+1 entries)
#define PE (EE + 7 * NN)                   // padded CSR capacity

// ---------------- degree + per-edge rank (old value of the atomic) ----------------

__global__ void k_deg(const int* __restrict__ dst, int* __restrict__ deg,
                      int* __restrict__ rank) {
    int e = blockIdx.x * blockDim.x + threadIdx.x;
    if (e < EE) rank[e] = atomicAdd(&deg[dst[e]], 1);
}

// ---------------- scan over PADDED degrees -> local rowptr + block sums (+ dinv) ----------------

__global__ void __launch_bounds__(1024) k_scan1(const int* __restrict__ deg,
                                                int* __restrict__ rowptr,
                                                int* __restrict__ bsum,
                                                float* __restrict__ dinv) {
    int tid = threadIdx.x;
    int lane = tid & 63, w = tid >> 6;
    int i = blockIdx.x * 1024 + tid;
    int d = (i < NN) ? deg[i] : 0;
    if (i < NN)       dinv[i] = 1.0f / sqrtf((float)(d + 1));   // +1 self-loop
    else if (i == NN) dinv[i] = 0.0f;                           // zero row
    int v = (i < NN) ? ((d + 7) & ~7) : 0;                      // padded degree
    int x = v;                                                  // inclusive wave scan
#pragma unroll
    for (int off = 1; off < 64; off <<= 1) {
        int y = __shfl_up(x, off);
        if (lane >= off) x += y;
    }
    __shared__ int ws[16];
    if (lane == 63) ws[w] = x;
    __syncthreads();
    if (tid < 16) {
        int y = ws[tid];
        int z = y;
#pragma unroll
        for (int off = 1; off < 16; off <<= 1) {
            int t2 = __shfl_up(z, off);
            if (tid >= off) z += t2;
        }
        ws[tid] = z - y;                          // exclusive wave offsets
    }
    __syncthreads();
    int excl = x - v + ws[w];
    if (i <= NN) rowptr[i] = excl;                // block-local exclusive prefix
    if (tid == 1023) bsum[blockIdx.x] = excl + v; // block total
}

__global__ void __launch_bounds__(64) k_scan2(int* __restrict__ bsum) {
    int lane = threadIdx.x;
    int v = (lane < SCAN_NB) ? bsum[lane] : 0;
    int x = v;
#pragma unroll
    for (int off = 1; off < 64; off <<= 1) {
        int y = __shfl_up(x, off);
        if (lane >= off) x += y;
    }
    if (lane < SCAN_NB) bsum[lane] = x - v;       // exclusive block offsets
}

// ---------------- CSR fill: atomic-free edges + dummy padding + per-graph counts ----------------

__global__ void k_fill(const int* __restrict__ src, const int* __restrict__ dst,
                       const int* __restrict__ rank,
                       const int* __restrict__ rowptr, const int* __restrict__ bsum,
                       const int* __restrict__ deg, const int* __restrict__ batch,
                       int* __restrict__ csr_src, int* __restrict__ cnt) {
    int tid = blockIdx.x * blockDim.x + threadIdx.x;
    if (tid < EE) {
        int d = dst[tid];
        csr_src[rowptr[d] + bsum[d >> 10] + rank[tid]] = src[tid];
    } else if (tid < EE + NN) {
        int i = tid - EE;
        int dg = deg[i];
        int start = rowptr[i] + bsum[i >> 10] + dg;
        int pad = ((dg + 7) & ~7) - dg;
        for (int j = 0; j < pad; ++j) csr_src[start + j] = NN;   // dummy -> zero row
    } else if (tid < EE + 2 * NN) {
        atomicAdd(&cnt[batch[tid - EE - NN]], 1);
    }
}

// ---------------- dense transform: t' = (act(x) @ W) * dinv[row]; row NN zeroed ----------------

template<bool RELU>
__global__ void __launch_bounds__(256) k_xform(const float* __restrict__ x,
                                               const float* __restrict__ W,
                                               const float* __restrict__ dinv,
                                               float* __restrict__ t) {
    __shared__ float sW[64 * 64];   // 16 KB
    __shared__ float sX[32 * 65];   // padded
    int tid = threadIdx.x;
    for (int k = tid; k < 64 * 64; k += 256) sW[k] = W[k];
    int row0 = blockIdx.x * 32;
    for (int v = tid; v < 32 * 16; v += 256) {
        int r  = v >> 4;
        int k4 = (v & 15) * 4;
        int row = row0 + r;
        float4 val = make_float4(0.f, 0.f, 0.f, 0.f);
        if (row < NN) val = *(const float4*)(x + (size_t)row * 64 + k4);
        if (RELU) {
            val.x = fmaxf(val.x, 0.f); val.y = fmaxf(val.y, 0.f);
            val.z = fmaxf(val.z, 0.f); val.w = fmaxf(val.w, 0.f);
        }
        sX[r * 65 + k4 + 0] = val.x;
        sX[r * 65 + k4 + 1] = val.y;
        sX[r * 65 + k4 + 2] = val.z;
        sX[r * 65 + k4 + 3] = val.w;
    }
    __syncthreads();
    int r  = tid >> 3;        // 0..31
    int c0 = (tid & 7) * 8;   // 0,8,...,56
    float acc[8] = {0.f, 0.f, 0.f, 0.f, 0.f, 0.f, 0.f, 0.f};
    for (int k = 0; k < 64; ++k) {
        float xv = sX[r * 65 + k];
#pragma unroll
        for (int j = 0; j < 8; ++j) acc[j] = fmaf(xv, sW[k * 64 + c0 + j], acc[j]);
    }
    int row = row0 + r;
    if (row <= NN) {          // row NN: acc==0 -> writes zero row
        float dv = dinv[row];
#pragma unroll
        for (int j = 0; j < 8; ++j) acc[j] *= dv;
        float4* o = (float4*)(t + (size_t)row * 64 + c0);
        o[0] = make_float4(acc[0], acc[1], acc[2], acc[3]);
        o[1] = make_float4(acc[4], acc[5], acc[6], acc[7]);
    }
}

// ---------------- CSR gather: one wave per node, padded 8-deep batches, scalar idx loads ----
// out[i] = dinv[i] * (t'[i] + sum_{s in N(i)} t'[s]) + b

template<bool POOL>
__global__ void __launch_bounds__(256) k_gather(const float* __restrict__ t,
                                                const float* __restrict__ dinv,
                                                const int* __restrict__ rowptr,
                                                const int* __restrict__ bsum,
                                                const int* __restrict__ csr_src,
                                                const float* __restrict__ b,
                                                const int* __restrict__ batch,
                                                float* __restrict__ out) {
    int i = __builtin_amdgcn_readfirstlane((blockIdx.x * blockDim.x + threadIdx.x) >> 6);
    int c = threadIdx.x & 63;
    if (i >= NN) return;
    int e   = __builtin_amdgcn_readfirstlane(rowptr[i]     + bsum[i >> 10]);
    int end = __builtin_amdgcn_readfirstlane(rowptr[i + 1] + bsum[(i + 1) >> 10]);
    float acc = t[(size_t)i * 64 + c];            // self-loop (t' already *dinv[i])
    float a0 = 0.f, a1 = 0.f, a2 = 0.f, a3 = 0.f;
    for (; e < end; e += 8) {                     // rows padded to x8: no tails
        int s0 = csr_src[e + 0], s1 = csr_src[e + 1];
        int s2 = csr_src[e + 2], s3 = csr_src[e + 3];
        int s4 = csr_src[e + 4], s5 = csr_src[e + 5];
        int s6 = csr_src[e + 6], s7 = csr_src[e + 7];
        float v0 = t[(size_t)s0 * 64 + c], v1 = t[(size_t)s1 * 64 + c];
        float v2 = t[(size_t)s2 * 64 + c], v3 = t[(size_t)s3 * 64 + c];
        float v4 = t[(size_t)s4 * 64 + c], v5 = t[(size_t)s5 * 64 + c];
        float v6 = t[(size_t)s6 * 64 + c], v7 = t[(size_t)s7 * 64 + c];
        a0 += v0 + v4; a1 += v1 + v5; a2 += v2 + v6; a3 += v3 + v7;
    }
    acc += (a0 + a1) + (a2 + a3);
    float r = fmaf(acc, dinv[i], b[c]);
    if (POOL) {
        atomicAdd(&out[(size_t)batch[i] * 64 + c], fmaxf(r, 0.0f));
    } else {
        out[(size_t)i * 64 + c] = r;
    }
}

// ---------------- head: per-graph MLP, one wave per graph ----------------

__global__ void __launch_bounds__(64) k_head(const float* __restrict__ pooled,
                                             const int* __restrict__ cnt,
                                             const float* __restrict__ w1,
                                             const float* __restrict__ b1,
                                             const float* __restrict__ w2,
                                             const float* __restrict__ b2,
                                             float* __restrict__ out) {
    int g = blockIdx.x;
    int c = threadIdx.x;
    __shared__ float sp[64];
    float cf = fmaxf((float)cnt[g], 1.0f);
    sp[c] = pooled[(size_t)g * 64 + c] / cf;
    __syncthreads();
    float acc = b1[c];
    for (int k = 0; k < 64; ++k) acc = fmaf(sp[k], w1[k * 64 + c], acc);
    float h1 = fmaxf(acc, 0.0f);
    float p = h1 * w2[c];
#pragma unroll
    for (int off = 32; off > 0; off >>= 1) p += __shfl_down(p, off);
    if (c == 0) out[g] = p + b2[0];
}

// ---------------- launch ----------------

extern "C" void kernel_launch(void* const* d_in, const int* in_sizes, int n_in,
                              void* d_out, int out_size, void* d_ws, size_t ws_size,
                              hipStream_t stream) {
    const float* x      = (const float*)d_in[0];
    const int*   ei     = (const int*)d_in[1];
    const int*   batch  = (const int*)d_in[2];
    const float* W0     = (const float*)d_in[3];
    const float* b0     = (const float*)d_in[4];
    const float* W1     = (const float*)d_in[5];
    const float* b1     = (const float*)d_in[6];
    const float* W2     = (const float*)d_in[7];
    const float* b2     = (const float*)d_in[8];
    const float* lin1w  = (const float*)d_in[9];
    const float* lin1b  = (const float*)d_in[10];
    const float* lin2w  = (const float*)d_in[11];
    const float* lin2b  = (const float*)d_in[12];
    float* out = (float*)d_out;

    const int* src = ei;
    const int* dst = ei + EE;

    char* ws = (char*)d_ws;
    size_t off = 0;
    auto carve = [&](size_t bytes) {
        void* p = ws + off;
        off = (off + bytes + 255) & ~(size_t)255;
        return p;
    };
    // zero-initialized group first (single memset covers [0, zero_span))
    int*   deg      = (int*)carve((size_t)NN * 4);
    float* pooled   = (float*)carve((size_t)GG * 64 * 4);
    int*   cnt      = (int*)carve((size_t)GG * 4);
    size_t zero_span = off;
    float* dinv     = (float*)carve((size_t)(NN + 1) * 4);
    int*   rowptr   = (int*)carve((size_t)(NN + 1) * 4);
    int*   bsum     = (int*)carve((size_t)SCAN_NB * 4);
    int*   rank     = (int*)carve((size_t)EE * 4);
    int*   csr_src  = (int*)carve((size_t)PE * 4);
    float* bufT     = (float*)carve((size_t)(NN + 1) * 64 * 4);  // +1 zero row
    float* bufA     = (float*)carve((size_t)NN * 64 * 4);

    hipMemsetAsync(deg, 0, zero_span, stream);

    // ---- CSR build ----
    k_deg  <<<(EE + 255) / 256, 256, 0, stream>>>(dst, deg, rank);
    k_scan1<<<SCAN_NB, 1024, 0, stream>>>(deg, rowptr, bsum, dinv);
    k_scan2<<<1, 64, 0, stream>>>(bsum);
    k_fill <<<(EE + 2 * NN + 255) / 256, 256, 0, stream>>>(src, dst, rank, rowptr,
                                                           bsum, deg, batch,
                                                           csr_src, cnt);

    const int xgrid = (NN + 1 + 31) / 32;        // includes zero row NN
    const int ggrid = (NN * 64) / 256;           // one 64-lane wave per node

    // layer 0: x -> bufA
    k_xform<false><<<xgrid, 256, 0, stream>>>(x, W0, dinv, bufT);
    k_gather<false><<<ggrid, 256, 0, stream>>>(bufT, dinv, rowptr, bsum, csr_src,
                                               b0, batch, bufA);
    // layer 1
    k_xform<true><<<xgrid, 256, 0, stream>>>(bufA, W1, dinv, bufT);
    k_gather<false><<<ggrid, 256, 0, stream>>>(bufT, dinv, rowptr, bsum, csr_src,
                                               b1, batch, bufA);
    // layer 2: relu + mean-pool fused into gather
    k_xform<true><<<xgrid, 256, 0, stream>>>(bufA, W2, dinv, bufT);
    k_gather<true><<<ggrid, 256, 0, stream>>>(bufT, dinv, rowptr, bsum, csr_src,
                                              b2, batch, pooled);

    k_head<<<GG, 64, 0, stream>>>(pooled, cnt, lin1w, lin1b, lin2w, lin2b, out);
}

// Round 11
// 310.043 us; speedup vs baseline: 2.5291x; 1.0215x over previous
//
#include <hip/hip_runtime.h>
#include <math.h>

#define NN 50000
#define EE 800000
#define HH 64
#define GG 512
#define SCAN_NB ((NN + 1023) / 1024)       // 49 blocks (covers NN+1 entries)

// ---------------- degree + per-edge rank (old value of the atomic) ----------------

__global__ void k_deg(const int* __restrict__ dst, int* __restrict__ deg,
                      int* __restrict__ rank) {
    int e = blockIdx.x * blockDim.x + threadIdx.x;
    if (e < EE) rank[e] = atomicAdd(&deg[dst[e]], 1);
}

// ---------------- scan: deg -> block-local rowptr + block sums (+ dinv) ----------------

__global__ void __launch_bounds__(1024) k_scan1(const int* __restrict__ deg,
                                                int* __restrict__ rowptr,
                                                int* __restrict__ bsum,
                                                float* __restrict__ dinv) {
    int tid = threadIdx.x;
    int lane = tid & 63, w = tid >> 6;
    int i = blockIdx.x * 1024 + tid;
    int v = (i < NN) ? deg[i] : 0;
    if (i < NN)       dinv[i] = 1.0f / sqrtf((float)(v + 1));   // +1 self-loop
    else if (i == NN) dinv[i] = 0.0f;                           // zero row
    int x = v;                                                  // inclusive wave scan
#pragma unroll
    for (int off = 1; off < 64; off <<= 1) {
        int y = __shfl_up(x, off);
        if (lane >= off) x += y;
    }
    __shared__ int ws[16];
    if (lane == 63) ws[w] = x;
    __syncthreads();
    if (tid < 16) {
        int y = ws[tid];
        int z = y;
#pragma unroll
        for (int off = 1; off < 16; off <<= 1) {
            int t2 = __shfl_up(z, off);
            if (tid >= off) z += t2;
        }
        ws[tid] = z - y;                          // exclusive wave offsets
    }
    __syncthreads();
    int excl = x - v + ws[w];
    if (i <= NN) rowptr[i] = excl;                // block-local exclusive prefix
    if (tid == 1023) bsum[blockIdx.x] = excl + v; // block total
}

__global__ void __launch_bounds__(64) k_scan2(int* __restrict__ bsum) {
    int lane = threadIdx.x;
    int v = (lane < SCAN_NB) ? bsum[lane] : 0;
    int x = v;
#pragma unroll
    for (int off = 1; off < 64; off <<= 1) {
        int y = __shfl_up(x, off);
        if (lane >= off) x += y;
    }
    if (lane < SCAN_NB) bsum[lane] = x - v;       // exclusive block offsets
}

// ---------------- CSR fill: atomic-free edge scatter + per-graph counts ----------------

__global__ void k_fill(const int* __restrict__ src, const int* __restrict__ dst,
                       const int* __restrict__ rank,
                       const int* __restrict__ rowptr, const int* __restrict__ bsum,
                       const int* __restrict__ batch,
                       int* __restrict__ csr_src, int* __restrict__ cnt) {
    int tid = blockIdx.x * blockDim.x + threadIdx.x;
    if (tid < EE) {
        int d = dst[tid];
        csr_src[rowptr[d] + bsum[d >> 10] + rank[tid]] = src[tid];
    } else if (tid < EE + NN) {
        atomicAdd(&cnt[batch[tid - EE]], 1);
    }
}

// ---------------- dense transform: t' = (act(x) @ W) * dinv[row]; row NN zeroed ----------------

template<bool RELU>
__global__ void __launch_bounds__(256) k_xform(const float* __restrict__ x,
                                               const float* __restrict__ W,
                                               const float* __restrict__ dinv,
                                               float* __restrict__ t) {
    __shared__ float sW[64 * 64];   // 16 KB
    __shared__ float sX[32 * 65];   // padded
    int tid = threadIdx.x;
    for (int k = tid; k < 64 * 64; k += 256) sW[k] = W[k];
    int row0 = blockIdx.x * 32;
    for (int v = tid; v < 32 * 16; v += 256) {
        int r  = v >> 4;
        int k4 = (v & 15) * 4;
        int row = row0 + r;
        float4 val = make_float4(0.f, 0.f, 0.f, 0.f);
        if (row < NN) val = *(const float4*)(x + (size_t)row * 64 + k4);
        if (RELU) {
            val.x = fmaxf(val.x, 0.f); val.y = fmaxf(val.y, 0.f);
            val.z = fmaxf(val.z, 0.f); val.w = fmaxf(val.w, 0.f);
        }
        sX[r * 65 + k4 + 0] = val.x;
        sX[r * 65 + k4 + 1] = val.y;
        sX[r * 65 + k4 + 2] = val.z;
        sX[r * 65 + k4 + 3] = val.w;
    }
    __syncthreads();
    int r  = tid >> 3;        // 0..31
    int c0 = (tid & 7) * 8;   // 0,8,...,56
    float acc[8] = {0.f, 0.f, 0.f, 0.f, 0.f, 0.f, 0.f, 0.f};
    for (int k = 0; k < 64; ++k) {
        float xv = sX[r * 65 + k];
#pragma unroll
        for (int j = 0; j < 8; ++j) acc[j] = fmaf(xv, sW[k * 64 + c0 + j], acc[j]);
    }
    int row = row0 + r;
    if (row <= NN) {          // row NN: acc==0 -> writes zero row
        float dv = dinv[row];
#pragma unroll
        for (int j = 0; j < 8; ++j) acc[j] *= dv;
        float4* o = (float4*)(t + (size_t)row * 64 + c0);
        o[0] = make_float4(acc[0], acc[1], acc[2], acc[3]);
        o[1] = make_float4(acc[4], acc[5], acc[6], acc[7]);
    }
}

// ---------------- CSR gather: one wave per node, 16-deep batches with uniform-masked tail ----
// out[i] = dinv[i] * (t'[i] + sum_{s in N(i)} t'[s]) + b

template<bool POOL>
__global__ void __launch_bounds__(256) k_gather(const float* __restrict__ t,
                                                const float* __restrict__ dinv,
                                                const int* __restrict__ rowptr,
                                                const int* __restrict__ bsum,
                                                const int* __restrict__ csr_src,
                                                const float* __restrict__ b,
                                                const int* __restrict__ batch,
                                                float* __restrict__ out) {
    int i = __builtin_amdgcn_readfirstlane((blockIdx.x * blockDim.x + threadIdx.x) >> 6);
    int c = threadIdx.x & 63;
    if (i >= NN) return;
    int e   = __builtin_amdgcn_readfirstlane(rowptr[i]     + bsum[i >> 10]);
    int end = __builtin_amdgcn_readfirstlane(rowptr[i + 1] + bsum[(i + 1) >> 10]);
    float acc = t[(size_t)i * 64 + c];            // self-loop (t' already *dinv[i])
    float a0 = 0.f, a1 = 0.f, a2 = 0.f, a3 = 0.f;
    for (; e < end; e += 16) {                    // 16 outstanding row-gathers
        int s[16];
#pragma unroll
        for (int j = 0; j < 16; ++j) {
            int sj = csr_src[e + j];              // uniform addr -> scalar load
            s[j] = (e + j < end) ? sj : NN;       // uniform select; NN = zero row
        }
        float v[16];
#pragma unroll
        for (int j = 0; j < 16; ++j) v[j] = t[(size_t)s[j] * 64 + c];
#pragma unroll
        for (int j = 0; j < 16; ++j) {
            if (j == 0)      a0 += v[0];
            else if (j == 1) a1 += v[1];
            else if (j == 2) a2 += v[2];
            else if (j == 3) a3 += v[3];
            else if ((j & 3) == 0) a0 += v[j];
            else if ((j & 3) == 1) a1 += v[j];
            else if ((j & 3) == 2) a2 += v[j];
            else                   a3 += v[j];
        }
    }
    acc += (a0 + a1) + (a2 + a3);
    float r = fmaf(acc, dinv[i], b[c]);
    if (POOL) {
        atomicAdd(&out[(size_t)batch[i] * 64 + c], fmaxf(r, 0.0f));
    } else {
        out[(size_t)i * 64 + c] = r;
    }
}

// ---------------- head: per-graph MLP, one wave per graph ----------------

__global__ void __launch_bounds__(64) k_head(const float* __restrict__ pooled,
                                             const int* __restrict__ cnt,
                                             const float* __restrict__ w1,
                                             const float* __restrict__ b1,
                                             const float* __restrict__ w2,
                                             const float* __restrict__ b2,
                                             float* __restrict__ out) {
    int g = blockIdx.x;
    int c = threadIdx.x;
    __shared__ float sp[64];
    float cf = fmaxf((float)cnt[g], 1.0f);
    sp[c] = pooled[(size_t)g * 64 + c] / cf;
    __syncthreads();
    float acc = b1[c];
    for (int k = 0; k < 64; ++k) acc = fmaf(sp[k], w1[k * 64 + c], acc);
    float h1 = fmaxf(acc, 0.0f);
    float p = h1 * w2[c];
#pragma unroll
    for (int off = 32; off > 0; off >>= 1) p += __shfl_down(p, off);
    if (c == 0) out[g] = p + b2[0];
}

// ---------------- launch ----------------

extern "C" void kernel_launch(void* const* d_in, const int* in_sizes, int n_in,
                              void* d_out, int out_size, void* d_ws, size_t ws_size,
                              hipStream_t stream) {
    const float* x      = (const float*)d_in[0];
    const int*   ei     = (const int*)d_in[1];
    const int*   batch  = (const int*)d_in[2];
    const float* W0     = (const float*)d_in[3];
    const float* b0     = (const float*)d_in[4];
    const float* W1     = (const float*)d_in[5];
    const float* b1     = (const float*)d_in[6];
    const float* W2     = (const float*)d_in[7];
    const float* b2     = (const float*)d_in[8];
    const float* lin1w  = (const float*)d_in[9];
    const float* lin1b  = (const float*)d_in[10];
    const float* lin2w  = (const float*)d_in[11];
    const float* lin2b  = (const float*)d_in[12];
    float* out = (float*)d_out;

    const int* src = ei;
    const int* dst = ei + EE;

    char* ws = (char*)d_ws;
    size_t off = 0;
    auto carve = [&](size_t bytes) {
        void* p = ws + off;
        off = (off + bytes + 255) & ~(size_t)255;
        return p;
    };
    // zero-initialized group first (single memset covers [0, zero_span))
    int*   deg      = (int*)carve((size_t)NN * 4);
    float* pooled   = (float*)carve((size_t)GG * 64 * 4);
    int*   cnt      = (int*)carve((size_t)GG * 4);
    size_t zero_span = off;
    float* dinv     = (float*)carve((size_t)(NN + 1) * 4);
    int*   rowptr   = (int*)carve((size_t)(NN + 1) * 4);
    int*   bsum     = (int*)carve((size_t)SCAN_NB * 4);
    int*   rank     = (int*)carve((size_t)EE * 4);
    int*   csr_src  = (int*)carve((size_t)(EE + 16) * 4);        // +16 for masked overrun reads
    float* bufT     = (float*)carve((size_t)(NN + 1) * 64 * 4);  // +1 zero row
    float* bufA     = (float*)carve((size_t)NN * 64 * 4);

    hipMemsetAsync(deg, 0, zero_span, stream);

    // ---- CSR build ----
    k_deg  <<<(EE + 255) / 256, 256, 0, stream>>>(dst, deg, rank);
    k_scan1<<<SCAN_NB, 1024, 0, stream>>>(deg, rowptr, bsum, dinv);
    k_scan2<<<1, 64, 0, stream>>>(bsum);
    k_fill <<<(EE + NN + 255) / 256, 256, 0, stream>>>(src, dst, rank, rowptr,
                                                       bsum, batch, csr_src, cnt);

    const int xgrid = (NN + 1 + 31) / 32;        // includes zero row NN
    const int ggrid = (NN * 64) / 256;           // one 64-lane wave per node

    // layer 0: x -> bufA
    k_xform<false><<<xgrid, 256, 0, stream>>>(x, W0, dinv, bufT);
    k_gather<false><<<ggrid, 256, 0, stream>>>(bufT, dinv, rowptr, bsum, csr_src,
                                               b0, batch, bufA);
    // layer 1
    k_xform<true><<<xgrid, 256, 0, stream>>>(bufA, W1, dinv, bufT);
    k_gather<false><<<ggrid, 256, 0, stream>>>(bufT, dinv, rowptr, bsum, csr_src,
                                               b1, batch, bufA);
    // layer 2: relu + mean-pool fused into gather
    k_xform<true><<<xgrid, 256, 0, stream>>>(bufA, W2, dinv, bufT);
    k_gather<true><<<ggrid, 256, 0, stream>>>(bufT, dinv, rowptr, bsum, csr_src,
                                              b2, batch, pooled);

    k_head<<<GG, 64, 0, stream>>>(pooled, cnt, lin1w, lin1b, lin2w, lin2b, out);
}

// Round 12
// 309.620 us; speedup vs baseline: 2.5325x; 1.0014x over previous
//
#include <hip/hip_runtime.h>
#include <math.h>

#define NN 50000
#define EE 800000
#define HH 64
#define GG 512
#define SCAN_NB ((NN + 1023) / 1024)       // 49 blocks (covers NN+1 entries)

typedef unsigned short ushort_t;
typedef unsigned int uint_t;

__device__ __forceinline__ ushort_t f32_to_bf16(float f) {
    uint_t u = __float_as_uint(f);
    uint_t bias = 0x7FFFu + ((u >> 16) & 1u);    // round-to-nearest-even
    return (ushort_t)((u + bias) >> 16);
}
__device__ __forceinline__ float bf16_to_f32(ushort_t h) {
    return __uint_as_float(((uint_t)h) << 16);
}

// ---------------- degree + per-edge rank (old value of the atomic) ----------------

__global__ void k_deg(const int* __restrict__ dst, int* __restrict__ deg,
                      int* __restrict__ rank) {
    int e = blockIdx.x * blockDim.x + threadIdx.x;
    if (e < EE) rank[e] = atomicAdd(&deg[dst[e]], 1);
}

// ---------------- scan: deg -> block-local rowptr + block sums (+ dinv) ----------------

__global__ void __launch_bounds__(1024) k_scan1(const int* __restrict__ deg,
                                                int* __restrict__ rowptr,
                                                int* __restrict__ bsum,
                                                float* __restrict__ dinv) {
    int tid = threadIdx.x;
    int lane = tid & 63, w = tid >> 6;
    int i = blockIdx.x * 1024 + tid;
    int v = (i < NN) ? deg[i] : 0;
    if (i < NN)       dinv[i] = 1.0f / sqrtf((float)(v + 1));   // +1 self-loop
    else if (i == NN) dinv[i] = 0.0f;                           // zero row
    int x = v;                                                  // inclusive wave scan
#pragma unroll
    for (int off = 1; off < 64; off <<= 1) {
        int y = __shfl_up(x, off);
        if (lane >= off) x += y;
    }
    __shared__ int ws[16];
    if (lane == 63) ws[w] = x;
    __syncthreads();
    if (tid < 16) {
        int y = ws[tid];
        int z = y;
#pragma unroll
        for (int off = 1; off < 16; off <<= 1) {
            int t2 = __shfl_up(z, off);
            if (tid >= off) z += t2;
        }
        ws[tid] = z - y;                          // exclusive wave offsets
    }
    __syncthreads();
    int excl = x - v + ws[w];
    if (i <= NN) rowptr[i] = excl;                // block-local exclusive prefix
    if (tid == 1023) bsum[blockIdx.x] = excl + v; // block total
}

__global__ void __launch_bounds__(64) k_scan2(int* __restrict__ bsum) {
    int lane = threadIdx.x;
    int v = (lane < SCAN_NB) ? bsum[lane] : 0;
    int x = v;
#pragma unroll
    for (int off = 1; off < 64; off <<= 1) {
        int y = __shfl_up(x, off);
        if (lane >= off) x += y;
    }
    if (lane < SCAN_NB) bsum[lane] = x - v;       // exclusive block offsets
}

// ---------------- CSR fill: atomic-free edge scatter + per-graph counts ----------------

__global__ void k_fill(const int* __restrict__ src, const int* __restrict__ dst,
                       const int* __restrict__ rank,
                       const int* __restrict__ rowptr, const int* __restrict__ bsum,
                       const int* __restrict__ batch,
                       int* __restrict__ csr_src, int* __restrict__ cnt) {
    int tid = blockIdx.x * blockDim.x + threadIdx.x;
    if (tid < EE) {
        int d = dst[tid];
        csr_src[rowptr[d] + bsum[d >> 10] + rank[tid]] = src[tid];
    } else if (tid < EE + NN) {
        atomicAdd(&cnt[batch[tid - EE]], 1);
    }
}

// ---------------- dense transform: t' = bf16((act(x) @ W) * dinv[row]); row NN zeroed ------

template<bool RELU>
__global__ void __launch_bounds__(256) k_xform(const float* __restrict__ x,
                                               const float* __restrict__ W,
                                               const float* __restrict__ dinv,
                                               ushort_t* __restrict__ t) {
    __shared__ float sW[64 * 64];   // 16 KB
    __shared__ float sX[32 * 65];   // padded
    int tid = threadIdx.x;
    for (int k = tid; k < 64 * 64; k += 256) sW[k] = W[k];
    int row0 = blockIdx.x * 32;
    for (int v = tid; v < 32 * 16; v += 256) {
        int r  = v >> 4;
        int k4 = (v & 15) * 4;
        int row = row0 + r;
        float4 val = make_float4(0.f, 0.f, 0.f, 0.f);
        if (row < NN) val = *(const float4*)(x + (size_t)row * 64 + k4);
        if (RELU) {
            val.x = fmaxf(val.x, 0.f); val.y = fmaxf(val.y, 0.f);
            val.z = fmaxf(val.z, 0.f); val.w = fmaxf(val.w, 0.f);
        }
        sX[r * 65 + k4 + 0] = val.x;
        sX[r * 65 + k4 + 1] = val.y;
        sX[r * 65 + k4 + 2] = val.z;
        sX[r * 65 + k4 + 3] = val.w;
    }
    __syncthreads();
    int r  = tid >> 3;        // 0..31
    int c0 = (tid & 7) * 8;   // 0,8,...,56
    float acc[8] = {0.f, 0.f, 0.f, 0.f, 0.f, 0.f, 0.f, 0.f};
    for (int k = 0; k < 64; ++k) {
        float xv = sX[r * 65 + k];
#pragma unroll
        for (int j = 0; j < 8; ++j) acc[j] = fmaf(xv, sW[k * 64 + c0 + j], acc[j]);
    }
    int row = row0 + r;
    if (row <= NN) {          // row NN: acc==0 -> writes zero row
        float dv = dinv[row];
        uint_t pk[4];
#pragma unroll
        for (int j = 0; j < 4; ++j) {
            ushort_t lo = f32_to_bf16(acc[2 * j] * dv);
            ushort_t hi = f32_to_bf16(acc[2 * j + 1] * dv);
            pk[j] = (uint_t)lo | ((uint_t)hi << 16);
        }
        uint4* o = (uint4*)(t + (size_t)row * 64 + c0);   // 16 B per lane
        *o = make_uint4(pk[0], pk[1], pk[2], pk[3]);
    }
}

// ---------------- CSR gather: one wave per node, 16-deep batches, bf16 rows ----------------
// out[i] = dinv[i] * (t'[i] + sum_{s in N(i)} t'[s]) + b

template<bool POOL>
__global__ void __launch_bounds__(256) k_gather(const ushort_t* __restrict__ t,
                                                const float* __restrict__ dinv,
                                                const int* __restrict__ rowptr,
                                                const int* __restrict__ bsum,
                                                const int* __restrict__ csr_src,
                                                const float* __restrict__ b,
                                                const int* __restrict__ batch,
                                                float* __restrict__ out) {
    int i = __builtin_amdgcn_readfirstlane((blockIdx.x * blockDim.x + threadIdx.x) >> 6);
    int c = threadIdx.x & 63;
    if (i >= NN) return;
    int e   = __builtin_amdgcn_readfirstlane(rowptr[i]     + bsum[i >> 10]);
    int end = __builtin_amdgcn_readfirstlane(rowptr[i + 1] + bsum[(i + 1) >> 10]);
    float acc = bf16_to_f32(t[(size_t)i * 64 + c]);   // self-loop (t' already *dinv[i])
    float a0 = 0.f, a1 = 0.f, a2 = 0.f, a3 = 0.f;
    for (; e < end; e += 16) {                    // 16 outstanding row-gathers
        int s[16];
#pragma unroll
        for (int j = 0; j < 16; ++j) {
            int sj = csr_src[e + j];              // uniform addr -> scalar load
            s[j] = (e + j < end) ? sj : NN;       // uniform select; NN = zero row
        }
        ushort_t v[16];
#pragma unroll
        for (int j = 0; j < 16; ++j) v[j] = t[(size_t)s[j] * 64 + c];
#pragma unroll
        for (int j = 0; j < 16; ++j) {
            float f = bf16_to_f32(v[j]);
            if ((j & 3) == 0)      a0 += f;
            else if ((j & 3) == 1) a1 += f;
            else if ((j & 3) == 2) a2 += f;
            else                   a3 += f;
        }
    }
    acc += (a0 + a1) + (a2 + a3);
    float r = fmaf(acc, dinv[i], b[c]);
    if (POOL) {
        atomicAdd(&out[(size_t)batch[i] * 64 + c], fmaxf(r, 0.0f));
    } else {
        out[(size_t)i * 64 + c] = r;
    }
}

// ---------------- head: per-graph MLP, one wave per graph ----------------

__global__ void __launch_bounds__(64) k_head(const float* __restrict__ pooled,
                                             const int* __restrict__ cnt,
                                             const float* __restrict__ w1,
                                             const float* __restrict__ b1,
                                             const float* __restrict__ w2,
                                             const float* __restrict__ b2,
                                             float* __restrict__ out) {
    int g = blockIdx.x;
    int c = threadIdx.x;
    __shared__ float sp[64];
    float cf = fmaxf((float)cnt[g], 1.0f);
    sp[c] = pooled[(size_t)g * 64 + c] / cf;
    __syncthreads();
    float acc = b1[c];
    for (int k = 0; k < 64; ++k) acc = fmaf(sp[k], w1[k * 64 + c], acc);
    float h1 = fmaxf(acc, 0.0f);
    float p = h1 * w2[c];
#pragma unroll
    for (int off = 32; off > 0; off >>= 1) p += __shfl_down(p, off);
    if (c == 0) out[g] = p + b2[0];
}

// ---------------- launch ----------------

extern "C" void kernel_launch(void* const* d_in, const int* in_sizes, int n_in,
                              void* d_out, int out_size, void* d_ws, size_t ws_size,
                              hipStream_t stream) {
    const float* x      = (const float*)d_in[0];
    const int*   ei     = (const int*)d_in[1];
    const int*   batch  = (const int*)d_in[2];
    const float* W0     = (const float*)d_in[3];
    const float* b0     = (const float*)d_in[4];
    const float* W1     = (const float*)d_in[5];
    const float* b1     = (const float*)d_in[6];
    const float* W2     = (const float*)d_in[7];
    const float* b2     = (const float*)d_in[8];
    const float* lin1w  = (const float*)d_in[9];
    const float* lin1b  = (const float*)d_in[10];
    const float* lin2w  = (const float*)d_in[11];
    const float* lin2b  = (const float*)d_in[12];
    float* out = (float*)d_out;

    const int* src = ei;
    const int* dst = ei + EE;

    char* ws = (char*)d_ws;
    size_t off = 0;
    auto carve = [&](size_t bytes) {
        void* p = ws + off;
        off = (off + bytes + 255) & ~(size_t)255;
        return p;
    };
    // zero-initialized group first (single memset covers [0, zero_span))
    int*      deg      = (int*)carve((size_t)NN * 4);
    float*    pooled   = (float*)carve((size_t)GG * 64 * 4);
    int*      cnt      = (int*)carve((size_t)GG * 4);
    size_t zero_span = off;
    float*    dinv     = (float*)carve((size_t)(NN + 1) * 4);
    int*      rowptr   = (int*)carve((size_t)(NN + 1) * 4);
    int*      bsum     = (int*)carve((size_t)SCAN_NB * 4);
    int*      rank     = (int*)carve((size_t)EE * 4);
    int*      csr_src  = (int*)carve((size_t)(EE + 16) * 4);     // +16 for masked overrun reads
    ushort_t* bufT     = (ushort_t*)carve((size_t)(NN + 1) * 64 * 2);  // bf16, +1 zero row
    float*    bufA     = (float*)carve((size_t)NN * 64 * 4);

    hipMemsetAsync(deg, 0, zero_span, stream);

    // ---- CSR build ----
    k_deg  <<<(EE + 255) / 256, 256, 0, stream>>>(dst, deg, rank);
    k_scan1<<<SCAN_NB, 1024, 0, stream>>>(deg, rowptr, bsum, dinv);
    k_scan2<<<1, 64, 0, stream>>>(bsum);
    k_fill <<<(EE + NN + 255) / 256, 256, 0, stream>>>(src, dst, rank, rowptr,
                                                       bsum, batch, csr_src, cnt);

    const int xgrid = (NN + 1 + 31) / 32;        // includes zero row NN
    const int ggrid = (NN * 64) / 256;           // one 64-lane wave per node

    // layer 0: x -> bufA
    k_xform<false><<<xgrid, 256, 0, stream>>>(x, W0, dinv, bufT);
    k_gather<false><<<ggrid, 256, 0, stream>>>(bufT, dinv, rowptr, bsum, csr_src,
                                               b0, batch, bufA);
    // layer 1
    k_xform<true><<<xgrid, 256, 0, stream>>>(bufA, W1, dinv, bufT);
    k_gather<false><<<ggrid, 256, 0, stream>>>(bufT, dinv, rowptr, bsum, csr_src,
                                               b1, batch, bufA);
    // layer 2: relu + mean-pool fused into gather
    k_xform<true><<<xgrid, 256, 0, stream>>>(bufA, W2, dinv, bufT);
    k_gather<true><<<ggrid, 256, 0, stream>>>(bufT, dinv, rowptr, bsum, csr_src,
                                              b2, batch, pooled);

    k_head<<<GG, 64, 0, stream>>>(pooled, cnt, lin1w, lin1b, lin2w, lin2b, out);
}